// Round 5
// baseline (541.323 us; speedup 1.0000x reference)
//
#include <hip/hip_runtime.h>
#include <hip/hip_bf16.h>
#include <cstdint>

typedef __bf16 bf16_t;
typedef __attribute__((ext_vector_type(8))) __bf16 bf16x8;
typedef __attribute__((ext_vector_type(4))) __bf16 bf16x4;
typedef __attribute__((ext_vector_type(4))) float f32x4;

#define NEXP 8
#define DK   2048
#define DN   2816
#define DN2  5632
#define NP   8192
#define PPE  1024

// ---------- gather x rows by sorted_token_ids, convert to bf16 ----------
__global__ void k_gather(const float* __restrict__ x, const int* __restrict__ ids,
                         bf16_t* __restrict__ xg) {
    int i = blockIdx.x * blockDim.x + threadIdx.x;
    if (i >= NP * (DK / 4)) return;
    int p  = i >> 9;
    int c4 = i & 511;
    int tok = ids[p];
    float4 v = reinterpret_cast<const float4*>(x + (size_t)tok * DK)[c4];
    bf16x4 o = { (bf16_t)v.x, (bf16_t)v.y, (bf16_t)v.z, (bf16_t)v.w };
    *reinterpret_cast<bf16x4*>(xg + (size_t)p * DK + c4 * 4) = o;
}

// ---------- async global->LDS, 16B per lane (wave-uniform LDS base) ----------
__device__ __forceinline__ void gl2lds16(const bf16_t* g, bf16_t* l) {
    __builtin_amdgcn_global_load_lds(
        (__attribute__((address_space(1))) void*)(const_cast<bf16_t*>(g)),
        (__attribute__((address_space(3))) void*)(l), 16, 0, 0);
}

#define BARX()  __builtin_amdgcn_s_barrier()
#define LGKM0() asm volatile("s_waitcnt lgkmcnt(0)" ::: "memory")
#define VMW0()  asm volatile("s_waitcnt vmcnt(0)" ::: "memory")

// A: stage one 128-row half-tile via global_load_lds (pre-swizzled source)
#define STGA(BUF, HALF, KT) do {                                                \
    gl2lds16(aSrc + (long)((HALF) * 128) * lda + (long)(KT) * 64,               \
             &As[BUF][(HALF) * 128 + w8][0]);                                   \
    gl2lds16(aSrc + (long)((HALF) * 128 + 64) * lda + (long)(KT) * 64,          \
             &As[BUF][(HALF) * 128 + 64 + w8][0]);                              \
} while (0)

// B: reg-staged fp32 -> bf16. Issue 64B contiguous per thread (4 x float4).
#define BISSUE(DST, BQ, KT) do {                                                \
    const float* p_ = (BQ) + (long)(KT) * 64;                                   \
    DST[0] = *reinterpret_cast<const float4*>(p_);                              \
    DST[1] = *reinterpret_cast<const float4*>(p_ + 4);                          \
    DST[2] = *reinterpret_cast<const float4*>(p_ + 8);                          \
    DST[3] = *reinterpret_cast<const float4*>(p_ + 12);                         \
} while (0)

// convert 16 floats -> 16 bf16, write two swizzled ds_write_b128
#define BWRITE(SRC, BUF, HALF) do {                                             \
    bf16x8 lo_ = { (bf16_t)SRC[0].x, (bf16_t)SRC[0].y, (bf16_t)SRC[0].z, (bf16_t)SRC[0].w, \
                   (bf16_t)SRC[1].x, (bf16_t)SRC[1].y, (bf16_t)SRC[1].z, (bf16_t)SRC[1].w }; \
    bf16x8 hi_ = { (bf16_t)SRC[2].x, (bf16_t)SRC[2].y, (bf16_t)SRC[2].z, (bf16_t)SRC[2].w, \
                   (bf16_t)SRC[3].x, (bf16_t)SRC[3].y, (bf16_t)SRC[3].z, (bf16_t)SRC[3].w }; \
    *reinterpret_cast<bf16x8*>(&Bs[BUF][(HALF) * 128 + trow][bc0sw]) = lo_;     \
    *reinterpret_cast<bf16x8*>(&Bs[BUF][(HALF) * 128 + trow][bc1sw]) = hi_;     \
} while (0)

#define LOADA(DST, BASE) do { _Pragma("unroll")                                 \
    for (int mi_ = 0; mi_ < 4; ++mi_) {                                         \
        DST[mi_][0] = *reinterpret_cast<const bf16x8*>((BASE) + aoff0 + mi_ * 1024); \
        DST[mi_][1] = *reinterpret_cast<const bf16x8*>((BASE) + aoff1 + mi_ * 1024); \
    } } while (0)

#define LOADB(DST, BASE) do { _Pragma("unroll")                                 \
    for (int ni_ = 0; ni_ < 2; ++ni_) {                                         \
        DST[ni_][0] = *reinterpret_cast<const bf16x8*>((BASE) + boff0 + ni_ * 1024); \
        DST[ni_][1] = *reinterpret_cast<const bf16x8*>((BASE) + boff1 + ni_ * 1024); \
    } } while (0)

#define MFMAQ(AF, BF, MIB, NIB) do {                                            \
    __builtin_amdgcn_s_setprio(1);                                              \
    _Pragma("unroll") for (int kk_ = 0; kk_ < 2; ++kk_)                         \
    _Pragma("unroll") for (int mi_ = 0; mi_ < 4; ++mi_)                         \
    _Pragma("unroll") for (int ni_ = 0; ni_ < 2; ++ni_)                         \
        acc[(MIB) + mi_][(NIB) + ni_] = __builtin_amdgcn_mfma_f32_16x16x32_bf16( \
            AF[mi_][kk_], BF[ni_][kk_], acc[(MIB) + mi_][(NIB) + ni_], 0, 0, 0); \
    __builtin_amdgcn_s_setprio(0);                                              \
} while (0)

// ---------- 256x256 8-phase BT GEMM; A via global_load_lds (bf16), B via
// reg-staged fp32->bf16 conversion fused into staging (no separate cvt pass).
// EPI=0: B rows map through the gate/up 16-row interleave of W1/W3;
//        epilogue writes h = sigmoid(gate)*up, bf16 [NP][DN].
// EPI=1: B = W2 [E][K][N] direct; epilogue atomicAdd-scatter into out fp32.
template <int EPI>
__launch_bounds__(512, 2)
__global__ void k_gemm(const bf16_t* __restrict__ A, const float* __restrict__ Bf1,
                       const float* __restrict__ Bf3,
                       bf16_t* __restrict__ Hout, float* __restrict__ Fout,
                       const float* __restrict__ tw, const int* __restrict__ ids,
                       int Mtiles, int Ntiles, int nkt, int lda, long aStride) {
    __shared__ bf16_t As[2][256][64];
    __shared__ bf16_t Bs[2][256][64];

    // XCD-bijective swizzle (grid % 8 == 0), nt-major within expert
    const int nwg = gridDim.x;
    const int logical = (blockIdx.x & 7) * (nwg >> 3) + (blockIdx.x >> 3);
    const int tpe = Mtiles * Ntiles;
    const int e  = logical / tpe;
    const int r  = logical - e * tpe;
    const int nt = r / Mtiles;          // B-panel sharers are consecutive
    const int mt = r - nt * Mtiles;

    const int tid  = threadIdx.x;
    const int w    = tid >> 6;
    const int w8   = w * 8;
    const int lane = tid & 63;
    const int wr = w >> 2, wc = w & 3;        // 2(M) x 4(N) waves, 128x64/wave
    const int fr = lane & 15;
    const int fc = lane >> 4;

    // A staging source: pre-swizzled global chunk (involution c' = c ^ (row&7))
    const int srow = tid >> 3;
    const int schk = (tid & 7) ^ (srow & 7);
    const bf16_t* aSrc = A + (long)e * aStride + ((long)mt * 256 + srow) * lda + schk * 8;

    // B staging: thread owns row trow of each half-tile, chunks tc0, tc0+1
    const int trow = tid >> 2;                  // 0..127
    const int tc0  = (tid & 3) * 2;
    const int bsw  = trow & 7;
    const int bc0sw = (tc0 ^ bsw) * 8;
    const int bc1sw = ((tc0 + 1) ^ bsw) * 8;
    const float* bQ0;
    const float* bQ1;
    if constexpr (EPI == 0) {
        // inverse of the gate/up interleave: n' -> (sel, n)
        int n0 = nt * 256 + trow;
        int n1 = n0 + 128;
        int s0 = (n0 >> 4) & 1, s1 = (n1 >> 4) & 1;
        int r0 = ((n0 >> 5) << 4) | (n0 & 15);
        int r1 = ((n1 >> 5) << 4) | (n1 & 15);
        bQ0 = (s0 ? Bf3 : Bf1) + ((long)e * DN + r0) * DK + tc0 * 8;
        bQ1 = (s1 ? Bf3 : Bf1) + ((long)e * DN + r1) * DK + tc0 * 8;
    } else {
        bQ0 = Bf1 + (long)e * DK * DN + ((long)nt * 256 + trow) * DN + tc0 * 8;
        bQ1 = bQ0 + 128L * DN;
    }

    // ds_read element offsets (swizzled)
    const int sx = lane & 7;
    const int aoff0 = (wr * 128 + fr) * 64 + ((0 + fc) ^ sx) * 8;
    const int aoff1 = (wr * 128 + fr) * 64 + ((4 + fc) ^ sx) * 8;
    const int boff0 = (wc * 64 + fr) * 64 + ((0 + fc) ^ sx) * 8;
    const int boff1 = (wc * 64 + fr) * 64 + ((4 + fc) ^ sx) * 8;

    const bf16_t* As0 = &As[0][0][0];
    const bf16_t* As1 = &As[1][0][0];
    const bf16_t* Bs0 = &Bs[0][0][0];
    const bf16_t* Bs1 = &Bs[1][0][0];

    bf16x8 af[4][2], ah[4][2], bl[2][2], bh[2][2];
    float4 bq[4];

    // ---- prologue: B(t0),B(t1) reg-staged; A(t0) + A0(t1) via gl2lds ----
    {
        float4 p0[4], p1[4], p2[4], p3[4];
        BISSUE(p0, bQ0, 0); BISSUE(p1, bQ1, 0);
        BISSUE(p2, bQ0, 1); BISSUE(p3, bQ1, 1);
        STGA(0, 0, 0); STGA(0, 1, 0);
        STGA(1, 0, 1);
        BWRITE(p0, 0, 0); BWRITE(p1, 0, 1);
        BWRITE(p2, 1, 0); BWRITE(p3, 1, 1);
        VMW0(); LGKM0();
    }
    BARX();

    f32x4 acc[8][4];
#pragma unroll
    for (int a = 0; a < 8; ++a)
#pragma unroll
        for (int b = 0; b < 4; ++b) acc[a][b] = (f32x4){0.f, 0.f, 0.f, 0.f};

    const int nIter = nkt >> 1;
    for (int it = 0; it < nIter; ++it) {
        const int t = it * 2;
        const bool last = (it == nIter - 1);
        // P1: read af,bl (buf0)
        LOADA(af, As0); LOADB(bl, Bs0);
        BARX(); LGKM0();
        MFMAQ(af, bl, 0, 0);
        BARX();
        // P2: read bh | issue B-lo(t+2) | glds A1(t+1)->buf1 | post: write B-lo->buf0
        LOADB(bh, Bs0 + 2048);
        if (!last) BISSUE(bq, bQ0, t + 2);
        STGA(1, 1, t + 1);
        BARX(); LGKM0();
        MFMAQ(af, bh, 0, 2);
        if (!last) BWRITE(bq, 0, 0);
        BARX();
        // P3: read ah | issue B-hi(t+2) | post: write B-hi->buf0
        LOADA(ah, As0 + 4096);
        if (!last) BISSUE(bq, bQ1, t + 2);
        BARX(); LGKM0();
        MFMAQ(ah, bh, 4, 2);
        if (!last) BWRITE(bq, 0, 1);
        BARX();
        // P4: glds A0(t+2)->buf0 (buf0.A free after P3)
        if (!last) STGA(0, 0, t + 2); else VMW0();
        BARX();
        MFMAQ(ah, bl, 4, 0);
        BARX();
        // P5: read af,bl (buf1) | glds A1(t+2)->buf0
        LOADA(af, As1); LOADB(bl, Bs1);
        if (!last) STGA(0, 1, t + 2);
        BARX(); LGKM0();
        MFMAQ(af, bl, 0, 0);
        BARX();
        // P6: read bh | issue B-lo(t+3) | post: write B-lo->buf1
        LOADB(bh, Bs1 + 2048);
        if (!last) BISSUE(bq, bQ0, t + 3);
        BARX(); LGKM0();
        MFMAQ(af, bh, 0, 2);
        if (!last) BWRITE(bq, 1, 0);
        BARX();
        // P7: read ah | issue B-hi(t+3) | post: write B-hi->buf1
        LOADA(ah, As1 + 4096);
        if (!last) BISSUE(bq, bQ1, t + 3);
        BARX(); LGKM0();
        MFMAQ(ah, bh, 4, 2);
        if (!last) BWRITE(bq, 1, 1);
        BARX();
        // P8: glds A0(t+3)->buf1 (buf1.A free after P7)
        if (!last) STGA(1, 0, t + 3);
        BARX();
        MFMAQ(ah, bl, 4, 0);
        BARX();
    }

    if constexpr (EPI == 0) {
        // interleaved cols: ni even = gate, ni odd = up (same real n)
        const long prow0 = (long)e * PPE + (long)mt * 256 + wr * 128 + fc * 4;
        const int col0 = nt * 128 + wc * 32 + fr;
#pragma unroll
        for (int mi = 0; mi < 8; ++mi)
#pragma unroll
            for (int i = 0; i < 4; ++i) {
                long row = prow0 + mi * 16 + i;
#pragma unroll
                for (int p = 0; p < 2; ++p) {
                    float g = acc[mi][2 * p][i];
                    float u = acc[mi][2 * p + 1][i];
                    float s = 1.f / (1.f + __expf(-g));
                    Hout[row * DN + col0 + p * 16] = (bf16_t)(s * u);
                }
            }
    } else {
        const int p0 = e * PPE + mt * 256 + wr * 128 + fc * 4;
        const int col0 = nt * 256 + wc * 64 + fr;
#pragma unroll
        for (int mi = 0; mi < 8; ++mi)
#pragma unroll
            for (int i = 0; i < 4; ++i) {
                int gp = p0 + mi * 16 + i;
                float wgt = tw[gp];
                float* ob = Fout + (long)ids[gp] * DK + col0;
#pragma unroll
                for (int ni = 0; ni < 4; ++ni)
                    atomicAdd(ob + ni * 16, acc[mi][ni][i] * wgt);
            }
    }
}

extern "C" void kernel_launch(void* const* d_in, const int* in_sizes, int n_in,
                              void* d_out, int out_size, void* d_ws, size_t ws_size,
                              hipStream_t stream) {
    const float* x   = (const float*)d_in[0];
    const float* W1  = (const float*)d_in[1];
    const float* W3  = (const float*)d_in[2];
    const float* W2  = (const float*)d_in[3];
    const float* tw  = (const float*)d_in[4];
    const int*   sid = (const int*)d_in[5];
    float* out = (float*)d_out;

    // workspace: xg 32MB, h 44MB
    char* ws = (char*)d_ws;
    bf16_t* xg = (bf16_t*)ws;
    bf16_t* h  = (bf16_t*)(ws + 33554432L);

    hipMemsetAsync(d_out, 0, (size_t)out_size * sizeof(float), stream);
    k_gather<<<NP * (DK / 4) / 256, 256, 0, stream>>>(x, sid, xg);

    // GEMM1+act: h = sigmoid(xg.W1^T) * (xg.W3^T); W1/W3 read fp32 directly
    k_gemm<0><<<NEXP * 4 * 22, 512, 0, stream>>>(
        xg, W1, W3, h, nullptr, nullptr, nullptr,
        4, 22, 32, DK, (long)PPE * DK);

    // GEMM2: out[tok,k] += tw[p] * h[p,:] . W2[e,k,:]^T; W2 read fp32 directly
    k_gemm<1><<<NEXP * 4 * 8, 512, 0, stream>>>(
        h, W2, nullptr, nullptr, out, tw, sid,
        4, 8, 44, DN, (long)PPE * DN);
}

// Round 6
// 530.758 us; speedup vs baseline: 1.0199x; 1.0199x over previous
//
#include <hip/hip_runtime.h>
#include <hip/hip_bf16.h>
#include <cstdint>

typedef __bf16 bf16_t;
typedef __attribute__((ext_vector_type(8))) __bf16 bf16x8;
typedef __attribute__((ext_vector_type(4))) __bf16 bf16x4;
typedef __attribute__((ext_vector_type(4))) float f32x4;

#define NEXP 8
#define DK   2048
#define DN   2816
#define DN2  5632
#define NP   8192
#define PPE  1024

// ---------- gather x rows by sorted_token_ids, convert to bf16 ----------
__global__ void k_gather(const float* __restrict__ x, const int* __restrict__ ids,
                         bf16_t* __restrict__ xg) {
    int i = blockIdx.x * blockDim.x + threadIdx.x;
    if (i >= NP * (DK / 4)) return;
    int p  = i >> 9;
    int c4 = i & 511;
    int tok = ids[p];
    float4 v = reinterpret_cast<const float4*>(x + (size_t)tok * DK)[c4];
    bf16x4 o = { (bf16_t)v.x, (bf16_t)v.y, (bf16_t)v.z, (bf16_t)v.w };
    *reinterpret_cast<bf16x4*>(xg + (size_t)p * DK + c4 * 4) = o;
}

// ---------- async global->LDS, 16B per lane (wave-uniform LDS base) ----------
__device__ __forceinline__ void gl2lds16(const bf16_t* g, bf16_t* l) {
    __builtin_amdgcn_global_load_lds(
        (__attribute__((address_space(1))) void*)(const_cast<bf16_t*>(g)),
        (__attribute__((address_space(3))) void*)(l), 16, 0, 0);
}

#define BARX()  __builtin_amdgcn_s_barrier()
#define LGKM0() asm volatile("s_waitcnt lgkmcnt(0)" ::: "memory")
#define VMW0()  asm volatile("s_waitcnt vmcnt(0)" ::: "memory")

// A: stage one 128-row half-tile via global_load_lds (pre-swizzled source)
#define STGA(BUF, HALF, KT) do {                                                \
    gl2lds16(aSrc + (long)((HALF) * 128) * lda + (long)(KT) * 64,               \
             &As[BUF][(HALF) * 128 + w8][0]);                                   \
    gl2lds16(aSrc + (long)((HALF) * 128 + 64) * lda + (long)(KT) * 64,          \
             &As[BUF][(HALF) * 128 + 64 + w8][0]);                              \
} while (0)

// B: reg-staged fp32 -> bf16. Issue 64B contiguous per thread (4 x float4).
#define BISSUE(DST, BQ, KT) do {                                                \
    const float* p_ = (BQ) + (long)(KT) * 64;                                   \
    DST[0] = *reinterpret_cast<const float4*>(p_);                              \
    DST[1] = *reinterpret_cast<const float4*>(p_ + 4);                          \
    DST[2] = *reinterpret_cast<const float4*>(p_ + 8);                          \
    DST[3] = *reinterpret_cast<const float4*>(p_ + 12);                         \
} while (0)

// convert 16 floats -> 16 bf16, write two swizzled ds_write_b128
#define BWRITE(SRC, BUF, HALF) do {                                             \
    bf16x8 lo_ = { (bf16_t)SRC[0].x, (bf16_t)SRC[0].y, (bf16_t)SRC[0].z, (bf16_t)SRC[0].w, \
                   (bf16_t)SRC[1].x, (bf16_t)SRC[1].y, (bf16_t)SRC[1].z, (bf16_t)SRC[1].w }; \
    bf16x8 hi_ = { (bf16_t)SRC[2].x, (bf16_t)SRC[2].y, (bf16_t)SRC[2].z, (bf16_t)SRC[2].w, \
                   (bf16_t)SRC[3].x, (bf16_t)SRC[3].y, (bf16_t)SRC[3].z, (bf16_t)SRC[3].w }; \
    *reinterpret_cast<bf16x8*>(&Bs[BUF][(HALF) * 128 + trow][bc0sw]) = lo_;     \
    *reinterpret_cast<bf16x8*>(&Bs[BUF][(HALF) * 128 + trow][bc1sw]) = hi_;     \
} while (0)

#define LOADA(DST, BASE) do { _Pragma("unroll")                                 \
    for (int mi_ = 0; mi_ < 4; ++mi_) {                                         \
        DST[mi_][0] = *reinterpret_cast<const bf16x8*>((BASE) + aoff0 + mi_ * 1024); \
        DST[mi_][1] = *reinterpret_cast<const bf16x8*>((BASE) + aoff1 + mi_ * 1024); \
    } } while (0)

#define LOADB(DST, BASE) do { _Pragma("unroll")                                 \
    for (int ni_ = 0; ni_ < 2; ++ni_) {                                         \
        DST[ni_][0] = *reinterpret_cast<const bf16x8*>((BASE) + boff0 + ni_ * 1024); \
        DST[ni_][1] = *reinterpret_cast<const bf16x8*>((BASE) + boff1 + ni_ * 1024); \
    } } while (0)

#define MFMAQ(AF, BF, MIB, NIB) do {                                            \
    __builtin_amdgcn_s_setprio(1);                                              \
    _Pragma("unroll") for (int kk_ = 0; kk_ < 2; ++kk_)                         \
    _Pragma("unroll") for (int mi_ = 0; mi_ < 4; ++mi_)                         \
    _Pragma("unroll") for (int ni_ = 0; ni_ < 2; ++ni_)                         \
        acc[(MIB) + mi_][(NIB) + ni_] = __builtin_amdgcn_mfma_f32_16x16x32_bf16( \
            AF[mi_][kk_], BF[ni_][kk_], acc[(MIB) + mi_][(NIB) + ni_], 0, 0, 0); \
    __builtin_amdgcn_s_setprio(0);                                              \
} while (0)

// ---------- 256x256 8-phase BT GEMM; A via global_load_lds (bf16), B via
// reg-staged fp32->bf16 fused conversion. FIFO-disciplined staging map:
//   P1: BISSUE bq  = B.h0(t+2)      (oldest of window)
//   P2: BISSUE bq2 = B.h1(t+2)
//   P3: BWRITE bq  -> buf0.B.h0     (implicit vmcnt(4): leaves bq2)
//   P4: STGA A(t+2) x2 -> buf0.A; BWRITE bq2 -> buf0.B.h1 (vmcnt(4): leaves A)
//   P5-P8: mirror for buf1 / t+3; P8 orders STGA before BWRITE so A(t+3)
//   stays in flight across the iteration boundary.
// Region ledger: B halves free after P2/P6, A halves after P3/P7 (bl/bh and
// af/ah each span both 128-row halves); every write >=1 barrier after last
// reader, every read covered by a vmcnt drain >=2 phases after issue.
// EPI=0: gate/up-interleaved B (W1/W3), epilogue h = sigmoid(g)*u -> bf16.
// EPI=1: B = W2 direct, epilogue atomicAdd-scatter into out fp32.
template <int EPI>
__launch_bounds__(512, 2)
__global__ void k_gemm(const bf16_t* __restrict__ A, const float* __restrict__ Bf1,
                       const float* __restrict__ Bf3,
                       bf16_t* __restrict__ Hout, float* __restrict__ Fout,
                       const float* __restrict__ tw, const int* __restrict__ ids,
                       int Mtiles, int Ntiles, int nkt, int lda, long aStride) {
    __shared__ bf16_t As[2][256][64];
    __shared__ bf16_t Bs[2][256][64];

    // XCD-bijective swizzle (grid % 8 == 0), nt-major within expert
    const int nwg = gridDim.x;
    const int logical = (blockIdx.x & 7) * (nwg >> 3) + (blockIdx.x >> 3);
    const int tpe = Mtiles * Ntiles;
    const int e  = logical / tpe;
    const int r  = logical - e * tpe;
    const int nt = r / Mtiles;          // B-panel sharers are consecutive
    const int mt = r - nt * Mtiles;

    const int tid  = threadIdx.x;
    const int w    = tid >> 6;
    const int w8   = w * 8;
    const int lane = tid & 63;
    const int wr = w >> 2, wc = w & 3;        // 2(M) x 4(N) waves, 128x64/wave
    const int fr = lane & 15;
    const int fc = lane >> 4;

    // A staging source: pre-swizzled global chunk (involution c' = c ^ (row&7))
    const int srow = tid >> 3;
    const int schk = (tid & 7) ^ (srow & 7);
    const bf16_t* aSrc = A + (long)e * aStride + ((long)mt * 256 + srow) * lda + schk * 8;

    // B staging: thread owns row trow of each half-tile, chunks tc0, tc0+1
    const int trow = tid >> 2;                  // 0..127
    const int tc0  = (tid & 3) * 2;
    const int bsw  = trow & 7;
    const int bc0sw = (tc0 ^ bsw) * 8;
    const int bc1sw = ((tc0 + 1) ^ bsw) * 8;
    const float* bQ0;
    const float* bQ1;
    if constexpr (EPI == 0) {
        // inverse of the gate/up interleave: n' -> (sel, n)
        int n0 = nt * 256 + trow;
        int n1 = n0 + 128;
        int s0 = (n0 >> 4) & 1, s1 = (n1 >> 4) & 1;
        int r0 = ((n0 >> 5) << 4) | (n0 & 15);
        int r1 = ((n1 >> 5) << 4) | (n1 & 15);
        bQ0 = (s0 ? Bf3 : Bf1) + ((long)e * DN + r0) * DK + tc0 * 8;
        bQ1 = (s1 ? Bf3 : Bf1) + ((long)e * DN + r1) * DK + tc0 * 8;
    } else {
        bQ0 = Bf1 + (long)e * DK * DN + ((long)nt * 256 + trow) * DN + tc0 * 8;
        bQ1 = bQ0 + 128L * DN;
    }

    // ds_read element offsets (swizzled)
    const int sx = lane & 7;
    const int aoff0 = (wr * 128 + fr) * 64 + ((0 + fc) ^ sx) * 8;
    const int aoff1 = (wr * 128 + fr) * 64 + ((4 + fc) ^ sx) * 8;
    const int boff0 = (wc * 64 + fr) * 64 + ((0 + fc) ^ sx) * 8;
    const int boff1 = (wc * 64 + fr) * 64 + ((4 + fc) ^ sx) * 8;

    const bf16_t* As0 = &As[0][0][0];
    const bf16_t* As1 = &As[1][0][0];
    const bf16_t* Bs0 = &Bs[0][0][0];
    const bf16_t* Bs1 = &Bs[1][0][0];

    bf16x8 af[4][2], ah[4][2], bl[2][2], bh[2][2];
    float4 bq[4], bq2[4];

    // ---- prologue: B(t0),B(t1) reg-staged; A(t0),A(t1) via gl2lds; full drain ----
    {
        float4 p0[4], p1[4], p2[4], p3[4];
        BISSUE(p0, bQ0, 0); BISSUE(p1, bQ1, 0);
        BISSUE(p2, bQ0, 1); BISSUE(p3, bQ1, 1);
        STGA(0, 0, 0); STGA(0, 1, 0);
        STGA(1, 0, 1); STGA(1, 1, 1);
        BWRITE(p0, 0, 0); BWRITE(p1, 0, 1);
        BWRITE(p2, 1, 0); BWRITE(p3, 1, 1);
        VMW0(); LGKM0();
    }
    BARX();

    f32x4 acc[8][4];
#pragma unroll
    for (int a = 0; a < 8; ++a)
#pragma unroll
        for (int b = 0; b < 4; ++b) acc[a][b] = (f32x4){0.f, 0.f, 0.f, 0.f};

    const int nIter = nkt >> 1;
    for (int it = 0; it < nIter; ++it) {
        const int t = it * 2;
        const bool last = (it == nIter - 1);
        // P1: read af,bl (buf0) | issue B.h0(t+2)
        LOADA(af, As0); LOADB(bl, Bs0);
        if (!last) BISSUE(bq, bQ0, t + 2);
        BARX(); LGKM0();
        MFMAQ(af, bl, 0, 0);
        BARX();
        // P2: read bh | issue B.h1(t+2)
        LOADB(bh, Bs0 + 2048);
        if (!last) BISSUE(bq2, bQ1, t + 2);
        BARX(); LGKM0();
        MFMAQ(af, bh, 0, 2);
        BARX();
        // P3: read ah | write B.h0(t+2)->buf0 (vmcnt(4), bq2 stays in flight)
        LOADA(ah, As0 + 4096);
        if (!last) BWRITE(bq, 0, 0);
        BARX(); LGKM0();
        MFMAQ(ah, bh, 4, 2);
        BARX();
        // P4: stage A(t+2)->buf0 then write B.h1(t+2) (vmcnt(4), A stays in flight)
        if (!last) { STGA(0, 0, t + 2); STGA(0, 1, t + 2); BWRITE(bq2, 0, 1); }
        else VMW0();
        BARX();
        MFMAQ(ah, bl, 4, 0);
        BARX();
        // P5: read af,bl (buf1) | issue B.h0(t+3)
        LOADA(af, As1); LOADB(bl, Bs1);
        if (!last) BISSUE(bq, bQ0, t + 3);
        BARX(); LGKM0();
        MFMAQ(af, bl, 0, 0);
        BARX();
        // P6: read bh | issue B.h1(t+3)
        LOADB(bh, Bs1 + 2048);
        if (!last) BISSUE(bq2, bQ1, t + 3);
        BARX(); LGKM0();
        MFMAQ(af, bh, 0, 2);
        BARX();
        // P7: read ah | write B.h0(t+3)->buf1 (vmcnt(4) drains A(t+2): ready for next P1)
        LOADA(ah, As1 + 4096);
        if (!last) BWRITE(bq, 1, 0);
        BARX(); LGKM0();
        MFMAQ(ah, bh, 4, 2);
        BARX();
        // P8: stage A(t+3)->buf1 then write B.h1(t+3) (vmcnt(4), A(t+3) stays in flight)
        if (!last) { STGA(1, 0, t + 3); STGA(1, 1, t + 3); BWRITE(bq2, 1, 1); }
        BARX();
        MFMAQ(ah, bl, 4, 0);
        BARX();
    }

    if constexpr (EPI == 0) {
        // interleaved cols: ni even = gate, ni odd = up (same real n)
        const long prow0 = (long)e * PPE + (long)mt * 256 + wr * 128 + fc * 4;
        const int col0 = nt * 128 + wc * 32 + fr;
#pragma unroll
        for (int mi = 0; mi < 8; ++mi)
#pragma unroll
            for (int i = 0; i < 4; ++i) {
                long row = prow0 + mi * 16 + i;
#pragma unroll
                for (int p = 0; p < 2; ++p) {
                    float g = acc[mi][2 * p][i];
                    float u = acc[mi][2 * p + 1][i];
                    float s = 1.f / (1.f + __expf(-g));
                    Hout[row * DN + col0 + p * 16] = (bf16_t)(s * u);
                }
            }
    } else {
        const int p0 = e * PPE + mt * 256 + wr * 128 + fc * 4;
        const int col0 = nt * 256 + wc * 64 + fr;
#pragma unroll
        for (int mi = 0; mi < 8; ++mi)
#pragma unroll
            for (int i = 0; i < 4; ++i) {
                int gp = p0 + mi * 16 + i;
                float wgt = tw[gp];
                float* ob = Fout + (long)ids[gp] * DK + col0;
#pragma unroll
                for (int ni = 0; ni < 4; ++ni)
                    atomicAdd(ob + ni * 16, acc[mi][ni][i] * wgt);
            }
    }
}

extern "C" void kernel_launch(void* const* d_in, const int* in_sizes, int n_in,
                              void* d_out, int out_size, void* d_ws, size_t ws_size,
                              hipStream_t stream) {
    const float* x   = (const float*)d_in[0];
    const float* W1  = (const float*)d_in[1];
    const float* W3  = (const float*)d_in[2];
    const float* W2  = (const float*)d_in[3];
    const float* tw  = (const float*)d_in[4];
    const int*   sid = (const int*)d_in[5];
    float* out = (float*)d_out;

    // workspace: xg 32MB, h 44MB
    char* ws = (char*)d_ws;
    bf16_t* xg = (bf16_t*)ws;
    bf16_t* h  = (bf16_t*)(ws + 33554432L);

    hipMemsetAsync(d_out, 0, (size_t)out_size * sizeof(float), stream);
    k_gather<<<NP * (DK / 4) / 256, 256, 0, stream>>>(x, sid, xg);

    // GEMM1+act: h = sigmoid(xg.W1^T) * (xg.W3^T); W1/W3 read fp32 directly
    k_gemm<0><<<NEXP * 4 * 22, 512, 0, stream>>>(
        xg, W1, W3, h, nullptr, nullptr, nullptr,
        4, 22, 32, DK, (long)PPE * DK);

    // GEMM2: out[tok,k] += tw[p] * h[p,:] . W2[e,k,:]^T; W2 read fp32 directly
    k_gemm<1><<<NEXP * 4 * 8, 512, 0, stream>>>(
        h, W2, nullptr, nullptr, out, tw, sid,
        4, 8, 44, DN, (long)PPE * DN);
}